// Round 9
// baseline (941.643 us; speedup 1.0000x reference)
//
#include <hip/hip_runtime.h>

typedef _Float16 half8 __attribute__((ext_vector_type(8)));
typedef float floatx4 __attribute__((ext_vector_type(4)));

#define SCOPE_AGENT __HIP_MEMORY_SCOPE_AGENT

__device__ __forceinline__ float fast_sigmoid(float x) {
    return __builtin_amdgcn_rcpf(1.0f + __expf(-x));
}
__device__ __forceinline__ float fast_tanh(float x) {
    return 1.0f - 2.0f * __builtin_amdgcn_rcpf(__expf(2.0f * x) + 1.0f);
}

// LDS-only barrier (no vmem drain) — verified r2->r3.
template<bool MULTI_WAVE>
__device__ __forceinline__ void lds_publish_barrier() {
    asm volatile("" ::: "memory");
    __builtin_amdgcn_s_waitcnt(0xC07F);
    if constexpr (MULTI_WAVE) __builtin_amdgcn_s_barrier();
    asm volatile("" ::: "memory");
}

__device__ __forceinline__ unsigned int ld_flag(unsigned int* p) {
    return __hip_atomic_load(p, __ATOMIC_RELAXED, SCOPE_AGENT);
}
// block-uniform spin on flag, then acquire (tid0 fence + syncthreads)
__device__ __forceinline__ void wait_flag_blk(unsigned int* p, int tid) {
    if (tid == 0) {
        while (ld_flag(p) == 0u) __builtin_amdgcn_s_sleep(2);
        __threadfence();
    }
    __syncthreads();
}
__device__ __forceinline__ void wait_count_blk(unsigned int* p, unsigned int tgt, int tid) {
    if (tid == 0) {
        while (ld_flag(p) < tgt) __builtin_amdgcn_s_sleep(16);
        __threadfence();
    }
    __syncthreads();
}

// ---------------- pack kernel: Wk/b gemm frags + Wr rec frags + flag clear ----
template<int F_REAL, int XT, int U>
__device__ __forceinline__ void pack_one(int dir, int wave, int lane,
    const float* Wk_f, const float* b_f, const float* Wk_b, const float* b_b,
    half8* wf, float4* bf4)
{
    constexpr int N  = 4 * U;
    constexpr int NW = U / 16;
    const int quad = lane >> 4, l16 = lane & 15;
    const float* Wk = dir ? Wk_b : Wk_f;
    const float* bs = dir ? b_b  : b_f;
    const int ucol = wave * 16 + l16;
    const long base = ((long)(dir * NW + wave) * 64 + lane) * (4 * XT);
    #pragma unroll
    for (int g = 0; g < 4; g++) {
        const int n = g * U + ucol;
        #pragma unroll
        for (int kt = 0; kt < XT; kt++) {
            half8 h;
            #pragma unroll
            for (int j = 0; j < 8; j++) {
                const int k = kt * 32 + quad * 8 + j;
                h[j] = (k < F_REAL) ? (_Float16)Wk[k * N + n] : (_Float16)0;
            }
            wf[base + g * XT + kt] = h;
        }
    }
    float4 b;
    b.x = bs[0 * U + ucol]; b.y = bs[1 * U + ucol];
    b.z = bs[2 * U + ucol]; b.w = bs[3 * U + ucol];
    bf4[(dir * NW + wave) * 64 + lane] = b;
}

template<int U, int HT, int NW>
__device__ __forceinline__ void pack_wr(int u, const float* Wr_f, const float* Wr_b,
                                        half8* dst)
{
    constexpr int N = 4 * U;
    const int dir  = u / (NW * 64);
    const int rest = u - dir * (NW * 64);
    const int w    = rest >> 6;
    const int lane = rest & 63;
    const int quad = lane >> 4, l16 = lane & 15;
    const int ucol = w * 16 + l16;
    const float* Wr = dir ? Wr_b : Wr_f;
    const long base = ((long)(dir * NW + w) * 64 + lane) * (4 * HT);
    #pragma unroll
    for (int g = 0; g < 4; g++) {
        #pragma unroll
        for (int ht = 0; ht < HT; ht++) {
            half8 h;
            #pragma unroll
            for (int j = 0; j < 8; j++) {
                const int k = ht * 32 + quad * 8 + j;
                h[j] = (k < U) ? (_Float16)Wr[k * N + g * U + ucol] : (_Float16)0;
            }
            dst[base + g * HT + ht] = h;
        }
    }
}

__global__ __launch_bounds__(256)
void pack_all(const float* w1f_k, const float* w1f_b, const float* w1b_k, const float* w1b_b,
              const float* w2f_k, const float* w2f_b, const float* w2b_k, const float* w2b_b,
              const float* w3f_k, const float* w3f_b, const float* w3b_k, const float* w3b_b,
              const float* w1f_r, const float* w1b_r,
              const float* w2f_r, const float* w2b_r,
              const float* w3f_r, const float* w3b_r,
              half8* wf, float4* bf4, half8* wrf, unsigned int* flags)
{
    const int t = blockIdx.x * 256 + threadIdx.x;
    if (t < 512) {
        pack_one<78, 3, 64>(t >> 8, (t >> 6) & 3, t & 63,
                            w1f_k, w1f_b, w1b_k, w1b_b, wf, bf4);
    } else if (t < 768) {
        const int t2 = t - 512;
        pack_one<128, 4, 32>(t2 >> 7, (t2 >> 6) & 1, t2 & 63,
                             w2f_k, w2f_b, w2b_k, w2b_b, wf + 6144, bf4 + 512);
    } else if (t < 896) {
        const int t3 = t - 768;
        pack_one<64, 2, 16>(t3 >> 6, 0, t3 & 63,
                            w3f_k, w3f_b, w3b_k, w3b_b, wf + 10240, bf4 + 768);
    } else if (t < 1408) {
        pack_wr<64, 2, 4>(t - 896, w1f_r, w1b_r, wrf);
    } else if (t < 1664) {
        pack_wr<32, 1, 2>(t - 1408, w2f_r, w2b_r, wrf + 4096);
    } else if (t < 1792) {
        pack_wr<16, 1, 1>(t - 1664, w3f_r, w3b_r, wrf + 5120);
    }
    for (int i = t; i < 3 * 2048 + 4; i += 2048) flags[i] = 0u;   // flags + done ctrs
}

// ---------------- gemm phase (device func, runs inside mega) ------------------
// One layer's xz production by a gemm-role block. Groups of NW waves each own a
// (dir,bg); iterate tc chunks (chunk-0-first across the grid), publish per-chunk
// flags after release fence.
template<int F_REAL, int FP, int XT, int U, bool IN_F32, bool STAGE, int ITERS, int TCS>
__device__ void gemm_phase(int gb, const void* in_, const half8* wfseg,
                           const float4* bfseg, _Float16* xz,
                           unsigned int* lflags, _Float16* XS, int tid)
{
    constexpr int T  = 128;
    constexpr int NW = U / 16;
    constexpr int TG = NW * 64;
    constexpr int GROUPS = 4 / NW;
    constexpr int TPC = 8;
    constexpr int CPR = FP / 8, CH = 16 * CPR, SPT = (CH + TG - 1) / TG;
    constexpr int ROWP = FP + 8;

    const int wave = tid >> 6, lane = tid & 63, quad = lane >> 4, l16 = lane & 15;
    const int gq = wave / NW;            // group in block
    const int wg = wave - gq * NW;       // wave in group
    const int tid_g = tid & (TG - 1);
    const int slot = gb * GROUPS + gq;
    const int db = slot & 255, dir = db >> 7, bg = db & 127;
    const int tc0 = slot >> 8;

    _Float16* XSg = XS + gq * (2 * 16 * ROWP);

    const long wbase = ((long)(dir * NW + wg) * 64 + lane) * (4 * XT);
    half8 bf[4][XT];
    #pragma unroll
    for (int g = 0; g < 4; g++)
        #pragma unroll
        for (int kt = 0; kt < XT; kt++)
            bf[g][kt] = wfseg[wbase + g * XT + kt];
    const float4 b4 = bfseg[(dir * NW + wg) * 64 + lane];
    const float bias[4] = {b4.x, b4.y, b4.z, b4.w};

    const int brow   = bg * 8 + (l16 & 7);
    const int tsel_a = l16 >> 3;
    const int q2     = quad & 1;
    const int tsel_c = quad >> 1;

    auto compute_store = [&](int tp, const half8* a) {
        floatx4 acc[4];
        #pragma unroll
        for (int g = 0; g < 4; g++) {
            floatx4 v = {bias[g], bias[g], bias[g], bias[g]};
            acc[g] = v;
        }
        #pragma unroll
        for (int kt = 0; kt < XT; kt++)
            #pragma unroll
            for (int g = 0; g < 4; g++)
                acc[g] = __builtin_amdgcn_mfma_f32_16x16x32_f16(a[kt], bf[g][kt], acc[g], 0, 0, 0);
        half8 lo, hi;
        #pragma unroll
        for (int r = 0; r < 4; r++) {
            lo[r]     = (_Float16)acc[0][r];
            lo[4 + r] = (_Float16)acc[1][r];
            hi[r]     = (_Float16)acc[2][r];
            hi[4 + r] = (_Float16)acc[3][r];
        }
        const int t_c = 2 * tp + tsel_c;
        _Float16* op = xz + (((((long)db * T + t_c) * NW + wg) * 2 + q2) * 256 + l16 * 16);
        *(half8*)op       = lo;
        *(half8*)(op + 8) = hi;
    };

    for (int k = 0; k < ITERS; k++) {
        const int tc = tc0 + k * TCS;
        if constexpr (STAGE) {
            auto load_tile = [&](int tp, half8* sreg) {
                #pragma unroll
                for (int s = 0; s < SPT; s++) {
                    const int c = tid_g + s * TG;
                    if (c < CH) {
                        const int row = c / CPR, col = (c - row * CPR) * 8;
                        const int t_a = 2 * tp + (row >> 3);
                        const int t_x = dir ? (T - 1 - t_a) : t_a;
                        const long ro = ((long)(bg * 8 + (row & 7)) * T + t_x) * F_REAL;
                        half8 h;
                        if constexpr (IN_F32) {
                            const float* p = (const float*)in_ + ro + col;
                            #pragma unroll
                            for (int j = 0; j < 8; j += 2) {
                                float v0 = 0.0f, v1 = 0.0f;
                                if (col + j < F_REAL) {
                                    const float2 v = *(const float2*)(p + j);
                                    v0 = v.x; v1 = v.y;
                                }
                                h[j] = (_Float16)v0; h[j + 1] = (_Float16)v1;
                            }
                        } else {
                            h = *(const half8*)((const _Float16*)in_ + ro + col);
                        }
                        sreg[s] = h;
                    }
                }
            };
            auto stage_write = [&](int buf, const half8* sreg) {
                #pragma unroll
                for (int s = 0; s < SPT; s++) {
                    const int c = tid_g + s * TG;
                    if (c < CH) {
                        const int row = c / CPR, col = (c - row * CPR) * 8;
                        *(half8*)&XSg[buf * (16 * ROWP) + row * ROWP + col] = sreg[s];
                    }
                }
            };
            half8 sreg[2][SPT];
            load_tile(tc * TPC, sreg[0]);
            #pragma unroll
            for (int i = 0; i < TPC; i++) {
                const int tp = tc * TPC + i;
                stage_write(i & 1, sreg[i & 1]);
                if (i + 1 < TPC) load_tile(tp + 1, sreg[(i + 1) & 1]);
                lds_publish_barrier<true>();
                half8 a[XT];
                const _Float16* xb = &XSg[(i & 1) * (16 * ROWP) + l16 * ROWP];
                #pragma unroll
                for (int kt = 0; kt < XT; kt++)
                    a[kt] = *(const half8*)(xb + kt * 32 + quad * 8);
                compute_store(tp, a);
            }
        } else {
            auto load_a = [&](int tp, half8* a) {
                const int t_a = 2 * tp + tsel_a;
                const int t_x = dir ? (T - 1 - t_a) : t_a;
                const _Float16* p = (const _Float16*)in_ + ((long)brow * T + t_x) * F_REAL;
                #pragma unroll
                for (int kt = 0; kt < XT; kt++)
                    a[kt] = *(const half8*)(p + kt * 32 + quad * 8);
            };
            half8 areg[2][XT];
            load_a(tc * TPC, areg[0]);
            #pragma unroll
            for (int i = 0; i < TPC; i++) {
                const int tp = tc * TPC + i;
                if (i + 1 < TPC) load_a(tp + 1, areg[(i + 1) & 1]);
                compute_store(tp, areg[i & 1]);
            }
        }
        // publish this (db, tc) chunk: drain stores, flush L2, set flag
        __syncthreads();                       // drains vmcnt per wave
        if (tid == 0) __threadfence();         // wbl2: visible at LLC
        __syncthreads();
        if (tid_g == 0)
            __hip_atomic_store(&lflags[db * 8 + tc], 1u, __ATOMIC_RELEASE, SCOPE_AGENT);
    }
}

// ---------------- rec phase (device func, runs inside mega) -------------------
// r8 lstm_rec with: packed Wr frags, redundant waves (weff), per-chunk flag
// waits on the producer gemm, done-counter signal at end.
template<int U, int HT, bool SEQ_OUT>
__device__ void rec_phase(int rb, const _Float16* xz, const half8* wrseg,
                          _Float16* hseq, float* hlast,
                          unsigned int* lflags, unsigned int* done_ctr,
                          _Float16* HS, int tid)
{
    constexpr int T    = 128;
    constexpr int NW   = U / 16;
    constexpr int HROW = 72;

    const int wave = tid >> 6, lane = tid & 63, quad = lane >> 4, l16 = lane & 15;
    const int weff = wave & (NW - 1);
    const int db = rb, dir = db >> 7, bg = db & 127, bbase = bg * 8;

    for (int i = tid; i < 2 * 8 * HROW; i += 256) HS[i] = (_Float16)0;

    const half8* wr = wrseg + ((long)(dir * NW + weff) * 64 + lane) * (4 * HT);
    half8 bf[4][HT];
    #pragma unroll
    for (int g = 0; g < 4; g++)
        #pragma unroll
        for (int ht = 0; ht < HT; ht++)
            bf[g][ht] = wr[g * HT + ht];

    const int ucol = weff * 16 + l16;
    const int rowbase = (quad & 1) * 4 + (quad >> 1) * 2;
    const bool hi_rows = (quad & 2) != 0;
    float c_reg[2] = {0.0f, 0.0f};

    const long rec_base = ((long)db * T) * (NW * 512)
                        + ((long)weff * 2 + (quad & 1)) * 256 + l16 * 16;
    auto load_xz = [&](int t, half8* z) {
        const _Float16* p = xz + rec_base + (long)t * (NW * 512);  // tail overrun benign
        z[0] = *(const half8*)p;
        z[1] = *(const half8*)(p + 8);
    };

    const int tp0 = dir ? (T - 1) : 0;
    const long hs_stride = (long)T * (2 * U);
    _Float16* hs_ptr = SEQ_OUT
        ? hseq + ((long)(bbase + rowbase) * T + tp0) * (2 * U) + dir * U + ucol
        : nullptr;
    const long hs_delta = dir ? -(long)(2 * U) : (long)(2 * U);

    auto step = [&](int t, half8* z) {
        floatx4 acc[4];
        #pragma unroll
        for (int g = 0; g < 4; g++)
            #pragma unroll
            for (int r = 0; r < 4; r++)
                acc[g][r] = (float)z[g >> 1][(g & 1) * 4 + r];
        load_xz(t + 2, z);
        lds_publish_barrier<(NW > 1)>();
        const _Float16* hb = &HS[(t & 1) * (8 * HROW) + (l16 & 7) * HROW];
        #pragma unroll
        for (int ht = 0; ht < HT; ht++) {
            const half8 ha = *(const half8*)(hb + ht * 32 + quad * 8);
            #pragma unroll
            for (int g = 0; g < 4; g++)
                acc[g] = __builtin_amdgcn_mfma_f32_16x16x32_f16(ha, bf[g][ht], acc[g], 0, 0, 0);
        }
        float hq[2];
        #pragma unroll
        for (int s = 0; s < 2; s++) {
            const int r = hi_rows ? (2 + s) : s;
            const float ig = fast_sigmoid(acc[0][r]);
            const float fg = fast_sigmoid(acc[1][r]);
            const float gg = fast_tanh(acc[2][r]);
            const float og = fast_sigmoid(acc[3][r]);
            const float c  = fg * c_reg[s] + ig * gg;
            c_reg[s] = c;
            hq[s] = og * fast_tanh(c);
        }
        #pragma unroll
        for (int s = 0; s < 2; s++)
            HS[((t + 1) & 1) * (8 * HROW) + (rowbase + s) * HROW + ucol] = (_Float16)hq[s];
        if constexpr (SEQ_OUT) {
            #pragma unroll
            for (int s = 0; s < 2; s++)
                hs_ptr[s * hs_stride] = (_Float16)hq[s];
            hs_ptr += hs_delta;
        } else {
            if (t == T - 1) {
                #pragma unroll
                for (int s = 0; s < 2; s++)
                    hlast[(bbase + rowbase + s) * (2 * U) + dir * U + ucol] = hq[s];
            }
        }
    };

    wait_flag_blk(&lflags[db * 8 + 0], tid);     // chunk 0 ready
    half8 za[2], zb[2];
    load_xz(0, za);
    load_xz(1, zb);
    __syncthreads();                              // H zero-init visible

    for (int tt = 0; tt < T; tt += 2) {
        if ((tt & 15) == 14 && tt < 126)
            wait_flag_blk(&lflags[db * 8 + ((tt + 2) >> 4)], tid);
        step(tt,     za);
        step(tt + 1, zb);
    }
    __syncthreads();                              // drain hseq/hlast stores (all waves)
    if (tid == 0) {
        __threadfence();
        __hip_atomic_fetch_add(done_ctr, 1u, __ATOMIC_RELEASE, SCOPE_AGENT);
    }
}

// ---------------- megakernel ---------------------------------------------------
__global__ __launch_bounds__(256, 2)
void mega(const float* __restrict__ x,
          const half8* __restrict__ wf, const float4* __restrict__ bf4,
          const half8* __restrict__ wrf,
          _Float16* __restrict__ xz, _Float16* __restrict__ h1,
          _Float16* __restrict__ h2, float* __restrict__ h3,
          unsigned int* __restrict__ flags,
          const float* __restrict__ d3_w, const float* __restrict__ d3_b,
          const float* __restrict__ cls_w, const float* __restrict__ cls_b,
          float* __restrict__ out)
{
    __shared__ __align__(16) _Float16 XS[2 * 2 * 16 * 136];   // gemm staging (max: L2)
    __shared__ __align__(16) _Float16 HS[2 * 8 * 72];         // rec h double-buffer

    const int bid = blockIdx.x, tid = threadIdx.x;
    unsigned int* done = flags + 3 * 2048;

    if (bid < 256) {
        // ---- GEMM role ----
        gemm_phase<78, 96, 3, 64, true, true, 8, 1>(bid, x, wf, bf4, xz, flags, XS, tid);
        wait_count_blk(&done[0], 256u, tid);
        gemm_phase<128, 128, 4, 32, false, true, 4, 2>(bid, h1, wf + 6144, bf4 + 512,
                                                       xz, flags + 2048, XS, tid);
        wait_count_blk(&done[1], 256u, tid);
        gemm_phase<64, 64, 2, 16, false, false, 2, 4>(bid, h2, wf + 10240, bf4 + 768,
                                                      xz, flags + 4096, XS, tid);
    } else {
        // ---- REC role ----
        const int rb = bid - 256;
        rec_phase<64, 2, true >(rb, xz, wrf,        h1, nullptr, flags,        &done[0], HS, tid);
        rec_phase<32, 1, true >(rb, xz, wrf + 4096, h2, nullptr, flags + 2048, &done[1], HS, tid);
        rec_phase<16, 1, false>(rb, xz, wrf + 5120, nullptr, h3, flags + 4096, &done[2], HS, tid);
        // ---- dense head (needs all blocks' h3) ----
        wait_count_blk(&done[2], 256u, tid);
        if (tid < 4) {
            const int r = rb * 4 + tid;
            float h[32];
            #pragma unroll
            for (int k = 0; k < 32; k++) h[k] = h3[r * 32 + k];
            float d1[8];
            #pragma unroll
            for (int j = 0; j < 8; j++) {
                float a = d3_b[j];
                #pragma unroll
                for (int k = 0; k < 32; k++) a += h[k] * d3_w[k * 8 + j];
                d1[j] = fmaxf(a, 0.0f);
            }
            #pragma unroll
            for (int c = 0; c < 3; c++) {
                float s = cls_b[c];
                #pragma unroll
                for (int j = 0; j < 8; j++) s += d1[j] * cls_w[j * 3 + c];
                out[r * 3 + c] = 1.0f / (1.0f + __expf(-s));
            }
        }
    }
}

extern "C" void kernel_launch(void* const* d_in, const int* in_sizes, int n_in,
                              void* d_out, int out_size, void* d_ws, size_t ws_size,
                              hipStream_t stream) {
    const float* x     = (const float*)d_in[0];
    const float* w1f_k = (const float*)d_in[1];
    const float* w1f_r = (const float*)d_in[2];
    const float* w1f_b = (const float*)d_in[3];
    const float* w1b_k = (const float*)d_in[4];
    const float* w1b_r = (const float*)d_in[5];
    const float* w1b_b = (const float*)d_in[6];
    const float* w2f_k = (const float*)d_in[7];
    const float* w2f_r = (const float*)d_in[8];
    const float* w2f_b = (const float*)d_in[9];
    const float* w2b_k = (const float*)d_in[10];
    const float* w2b_r = (const float*)d_in[11];
    const float* w2b_b = (const float*)d_in[12];
    const float* w3f_k = (const float*)d_in[13];
    const float* w3f_r = (const float*)d_in[14];
    const float* w3f_b = (const float*)d_in[15];
    const float* w3b_k = (const float*)d_in[16];
    const float* w3b_r = (const float*)d_in[17];
    const float* w3b_b = (const float*)d_in[18];
    const float* d3_w  = (const float*)d_in[19];
    const float* d3_b  = (const float*)d_in[20];
    const float* cls_w = (const float*)d_in[21];
    const float* cls_b = (const float*)d_in[22];

    char* ws = (char*)d_ws;
    _Float16* xz = (_Float16*)ws;                                   // 134.2MB (+tail)
    _Float16* h1 = (_Float16*)(ws + 134217728);                     // 32MB
    _Float16* h2 = (_Float16*)(ws + 167772160);                     // 16.8MB
    float*    h3 = (float*)   (ws + 184549376);                     // 128KB
    const size_t B0 = 184680448;
    half8*       wf    = (half8*)      (ws + B0);                   // 176KB
    float4*      bf4   = (float4*)     (ws + B0 + 180224);          // 14KB
    half8*       wrf   = (half8*)      (ws + B0 + 196608);          // 88KB
    unsigned int* flags = (unsigned int*)(ws + B0 + 294912);        // 24KB + ctrs

    pack_all<<<dim3(8), dim3(256), 0, stream>>>(
        w1f_k, w1f_b, w1b_k, w1b_b, w2f_k, w2f_b, w2b_k, w2b_b,
        w3f_k, w3f_b, w3b_k, w3b_b,
        w1f_r, w1b_r, w2f_r, w2b_r, w3f_r, w3b_r,
        wf, bf4, wrf, flags);

    mega<<<dim3(512), dim3(256), 0, stream>>>(
        x, wf, bf4, wrf, xz, h1, h2, h3, flags,
        d3_w, d3_b, cls_w, cls_b, (float*)d_out);
}

// Round 10
// 889.844 us; speedup vs baseline: 1.0582x; 1.0582x over previous
//
#include <hip/hip_runtime.h>

typedef _Float16 half8 __attribute__((ext_vector_type(8)));
typedef float floatx4 __attribute__((ext_vector_type(4)));

#define SCOPE_AGENT __HIP_MEMORY_SCOPE_AGENT

__device__ __forceinline__ float fast_sigmoid(float x) {
    return __builtin_amdgcn_rcpf(1.0f + __expf(-x));
}
__device__ __forceinline__ float fast_tanh(float x) {
    return 1.0f - 2.0f * __builtin_amdgcn_rcpf(__expf(2.0f * x) + 1.0f);
}

// LDS-only barrier (no vmem drain) — verified r2->r3.
template<bool MULTI_WAVE>
__device__ __forceinline__ void lds_publish_barrier() {
    asm volatile("" ::: "memory");
    __builtin_amdgcn_s_waitcnt(0xC07F);
    if constexpr (MULTI_WAVE) __builtin_amdgcn_s_barrier();
    asm volatile("" ::: "memory");
}

__device__ __forceinline__ unsigned int ld_flag(unsigned int* p) {
    return __hip_atomic_load(p, __ATOMIC_RELAXED, SCOPE_AGENT);
}
__device__ __forceinline__ void wait_flag_blk(unsigned int* p, int tid) {
    if (tid == 0) {
        while (ld_flag(p) == 0u) __builtin_amdgcn_s_sleep(2);
        __threadfence();
    }
    __syncthreads();
}
__device__ __forceinline__ void wait_count_blk(unsigned int* p, unsigned int tgt, int tid) {
    if (tid == 0) {
        while (ld_flag(p) < tgt) __builtin_amdgcn_s_sleep(16);
        __threadfence();
    }
    __syncthreads();
}

// ---------------- pack kernel (r9, proven) ------------------------------------
template<int F_REAL, int XT, int U>
__device__ __forceinline__ void pack_one(int dir, int wave, int lane,
    const float* Wk_f, const float* b_f, const float* Wk_b, const float* b_b,
    half8* wf, float4* bf4)
{
    constexpr int N  = 4 * U;
    constexpr int NW = U / 16;
    const int quad = lane >> 4, l16 = lane & 15;
    const float* Wk = dir ? Wk_b : Wk_f;
    const float* bs = dir ? b_b  : b_f;
    const int ucol = wave * 16 + l16;
    const long base = ((long)(dir * NW + wave) * 64 + lane) * (4 * XT);
    #pragma unroll
    for (int g = 0; g < 4; g++) {
        const int n = g * U + ucol;
        #pragma unroll
        for (int kt = 0; kt < XT; kt++) {
            half8 h;
            #pragma unroll
            for (int j = 0; j < 8; j++) {
                const int k = kt * 32 + quad * 8 + j;
                h[j] = (k < F_REAL) ? (_Float16)Wk[k * N + n] : (_Float16)0;
            }
            wf[base + g * XT + kt] = h;
        }
    }
    float4 b;
    b.x = bs[0 * U + ucol]; b.y = bs[1 * U + ucol];
    b.z = bs[2 * U + ucol]; b.w = bs[3 * U + ucol];
    bf4[(dir * NW + wave) * 64 + lane] = b;
}

template<int U, int HT, int NW>
__device__ __forceinline__ void pack_wr(int u, const float* Wr_f, const float* Wr_b,
                                        half8* dst)
{
    constexpr int N = 4 * U;
    const int dir  = u / (NW * 64);
    const int rest = u - dir * (NW * 64);
    const int w    = rest >> 6;
    const int lane = rest & 63;
    const int quad = lane >> 4, l16 = lane & 15;
    const int ucol = w * 16 + l16;
    const float* Wr = dir ? Wr_b : Wr_f;
    const long base = ((long)(dir * NW + w) * 64 + lane) * (4 * HT);
    #pragma unroll
    for (int g = 0; g < 4; g++) {
        #pragma unroll
        for (int ht = 0; ht < HT; ht++) {
            half8 h;
            #pragma unroll
            for (int j = 0; j < 8; j++) {
                const int k = ht * 32 + quad * 8 + j;
                h[j] = (k < U) ? (_Float16)Wr[k * N + g * U + ucol] : (_Float16)0;
            }
            dst[base + g * HT + ht] = h;
        }
    }
}

__global__ __launch_bounds__(256)
void pack_all(const float* w1f_k, const float* w1f_b, const float* w1b_k, const float* w1b_b,
              const float* w2f_k, const float* w2f_b, const float* w2b_k, const float* w2b_b,
              const float* w3f_k, const float* w3f_b, const float* w3b_k, const float* w3b_b,
              const float* w1f_r, const float* w1b_r,
              const float* w2f_r, const float* w2b_r,
              const float* w3f_r, const float* w3b_r,
              half8* wf, float4* bf4, half8* wrf, unsigned int* flags)
{
    const int t = blockIdx.x * 256 + threadIdx.x;
    if (t < 512) {
        pack_one<78, 3, 64>(t >> 8, (t >> 6) & 3, t & 63,
                            w1f_k, w1f_b, w1b_k, w1b_b, wf, bf4);
    } else if (t < 768) {
        const int t2 = t - 512;
        pack_one<128, 4, 32>(t2 >> 7, (t2 >> 6) & 1, t2 & 63,
                             w2f_k, w2f_b, w2b_k, w2b_b, wf + 6144, bf4 + 512);
    } else if (t < 896) {
        const int t3 = t - 768;
        pack_one<64, 2, 16>(t3 >> 6, 0, t3 & 63,
                            w3f_k, w3f_b, w3b_k, w3b_b, wf + 10240, bf4 + 768);
    } else if (t < 1408) {
        pack_wr<64, 2, 4>(t - 896, w1f_r, w1b_r, wrf);
    } else if (t < 1664) {
        pack_wr<32, 1, 2>(t - 1408, w2f_r, w2b_r, wrf + 4096);
    } else if (t < 1792) {
        pack_wr<16, 1, 1>(t - 1664, w3f_r, w3b_r, wrf + 5120);
    }
    for (int i = t; i < 3 * 2048 + 4; i += 2048) flags[i] = 0u;   // flags + done ctrs
}

// ---------------- one gemm chunk: (db, tc) -> 8 t-pairs of xz -----------------
template<int F_REAL, int FP, int XT, int U, bool IN_F32, bool STAGE>
__device__ __forceinline__ void gemm_chunk(int db, int tc, const void* in_,
    const half8* wfseg, const float4* bfseg, _Float16* xz, _Float16* XSg,
    int wg, int lane, int tid_g)
{
    constexpr int T  = 128;
    constexpr int NW = U / 16;
    constexpr int TG = NW * 64;
    constexpr int TPC = 8;
    constexpr int CPR = FP / 8, CH = 16 * CPR, SPT = (CH + TG - 1) / TG;
    constexpr int ROWP = FP + 8;

    const int quad = lane >> 4, l16 = lane & 15;
    const int dir = db >> 7, bg = db & 127;

    const long wbase = ((long)(dir * NW + wg) * 64 + lane) * (4 * XT);
    half8 bf[4][XT];
    #pragma unroll
    for (int g = 0; g < 4; g++)
        #pragma unroll
        for (int kt = 0; kt < XT; kt++)
            bf[g][kt] = wfseg[wbase + g * XT + kt];
    const float4 b4 = bfseg[(dir * NW + wg) * 64 + lane];
    const float bias[4] = {b4.x, b4.y, b4.z, b4.w};

    const int q2     = quad & 1;
    const int tsel_c = quad >> 1;

    auto compute_store = [&](int tp, const half8* a) {
        floatx4 acc[4];
        #pragma unroll
        for (int g = 0; g < 4; g++) {
            floatx4 v = {bias[g], bias[g], bias[g], bias[g]};
            acc[g] = v;
        }
        #pragma unroll
        for (int kt = 0; kt < XT; kt++)
            #pragma unroll
            for (int g = 0; g < 4; g++)
                acc[g] = __builtin_amdgcn_mfma_f32_16x16x32_f16(a[kt], bf[g][kt], acc[g], 0, 0, 0);
        half8 lo, hi;
        #pragma unroll
        for (int r = 0; r < 4; r++) {
            lo[r]     = (_Float16)acc[0][r];
            lo[4 + r] = (_Float16)acc[1][r];
            hi[r]     = (_Float16)acc[2][r];
            hi[4 + r] = (_Float16)acc[3][r];
        }
        const int t_c = 2 * tp + tsel_c;
        _Float16* op = xz + (((((long)db * T + t_c) * NW + wg) * 2 + q2) * 256 + l16 * 16);
        *(half8*)op       = lo;
        *(half8*)(op + 8) = hi;
    };

    if constexpr (STAGE) {
        auto load_tile = [&](int tp, half8* sreg) {
            #pragma unroll
            for (int s = 0; s < SPT; s++) {
                const int c = tid_g + s * TG;
                if (c < CH) {
                    const int row = c / CPR, col = (c - row * CPR) * 8;
                    const int t_a = 2 * tp + (row >> 3);
                    const int t_x = dir ? (T - 1 - t_a) : t_a;
                    const long ro = ((long)(bg * 8 + (row & 7)) * T + t_x) * F_REAL;
                    half8 h;
                    if constexpr (IN_F32) {
                        const float* p = (const float*)in_ + ro + col;
                        #pragma unroll
                        for (int j = 0; j < 8; j += 2) {
                            float v0 = 0.0f, v1 = 0.0f;
                            if (col + j < F_REAL) {
                                const float2 v = *(const float2*)(p + j);
                                v0 = v.x; v1 = v.y;
                            }
                            h[j] = (_Float16)v0; h[j + 1] = (_Float16)v1;
                        }
                    } else {
                        h = *(const half8*)((const _Float16*)in_ + ro + col);
                    }
                    sreg[s] = h;
                }
            }
        };
        auto stage_write = [&](int buf, const half8* sreg) {
            #pragma unroll
            for (int s = 0; s < SPT; s++) {
                const int c = tid_g + s * TG;
                if (c < CH) {
                    const int row = c / CPR, col = (c - row * CPR) * 8;
                    *(half8*)&XSg[buf * (16 * ROWP) + row * ROWP + col] = sreg[s];
                }
            }
        };
        half8 sreg[2][SPT];
        load_tile(tc * TPC, sreg[0]);
        #pragma unroll
        for (int i = 0; i < TPC; i++) {
            const int tp = tc * TPC + i;
            stage_write(i & 1, sreg[i & 1]);
            if (i + 1 < TPC) load_tile(tp + 1, sreg[(i + 1) & 1]);
            lds_publish_barrier<true>();
            half8 a[XT];
            const _Float16* xb = &XSg[(i & 1) * (16 * ROWP) + l16 * ROWP];
            #pragma unroll
            for (int kt = 0; kt < XT; kt++)
                a[kt] = *(const half8*)(xb + kt * 32 + quad * 8);
            compute_store(tp, a);
        }
    } else {
        const int brow   = bg * 8 + (l16 & 7);
        const int tsel_a = l16 >> 3;
        auto load_a = [&](int tp, half8* a) {
            const int t_a = 2 * tp + tsel_a;
            const int t_x = dir ? (T - 1 - t_a) : t_a;
            const _Float16* p = (const _Float16*)in_ + ((long)brow * T + t_x) * F_REAL;
            #pragma unroll
            for (int kt = 0; kt < XT; kt++)
                a[kt] = *(const half8*)(p + kt * 32 + quad * 8);
        };
        half8 areg[2][XT];
        load_a(tc * TPC, areg[0]);
        #pragma unroll
        for (int i = 0; i < TPC; i++) {
            const int tp = tc * TPC + i;
            if (i + 1 < TPC) load_a(tp + 1, areg[(i + 1) & 1]);
            compute_store(tp, areg[i & 1]);
        }
    }
}

// ---------------- rec phase (r9, proven correct) ------------------------------
template<int U, int HT, bool SEQ_OUT>
__device__ void rec_phase(int rb, const _Float16* xz, const half8* wrseg,
                          _Float16* hseq, float* hlast,
                          unsigned int* lflags, unsigned int* done_ctr,
                          _Float16* HS, int tid)
{
    constexpr int T    = 128;
    constexpr int NW   = U / 16;
    constexpr int HROW = 72;

    const int wave = tid >> 6, lane = tid & 63, quad = lane >> 4, l16 = lane & 15;
    const int weff = wave & (NW - 1);
    const int db = rb, dir = db >> 7, bg = db & 127, bbase = bg * 8;

    for (int i = tid; i < 2 * 8 * HROW; i += 256) HS[i] = (_Float16)0;

    const half8* wr = wrseg + ((long)(dir * NW + weff) * 64 + lane) * (4 * HT);
    half8 bf[4][HT];
    #pragma unroll
    for (int g = 0; g < 4; g++)
        #pragma unroll
        for (int ht = 0; ht < HT; ht++)
            bf[g][ht] = wr[g * HT + ht];

    const int ucol = weff * 16 + l16;
    const int rowbase = (quad & 1) * 4 + (quad >> 1) * 2;
    const bool hi_rows = (quad & 2) != 0;
    float c_reg[2] = {0.0f, 0.0f};

    const long rec_base = ((long)db * T) * (NW * 512)
                        + ((long)weff * 2 + (quad & 1)) * 256 + l16 * 16;
    auto load_xz = [&](int t, half8* z) {
        const _Float16* p = xz + rec_base + (long)t * (NW * 512);  // tail overrun benign
        z[0] = *(const half8*)p;
        z[1] = *(const half8*)(p + 8);
    };

    const int tp0 = dir ? (T - 1) : 0;
    const long hs_stride = (long)T * (2 * U);
    _Float16* hs_ptr = SEQ_OUT
        ? hseq + ((long)(bbase + rowbase) * T + tp0) * (2 * U) + dir * U + ucol
        : nullptr;
    const long hs_delta = dir ? -(long)(2 * U) : (long)(2 * U);

    auto step = [&](int t, half8* z) {
        floatx4 acc[4];
        #pragma unroll
        for (int g = 0; g < 4; g++)
            #pragma unroll
            for (int r = 0; r < 4; r++)
                acc[g][r] = (float)z[g >> 1][(g & 1) * 4 + r];
        load_xz(t + 2, z);
        lds_publish_barrier<(NW > 1)>();
        const _Float16* hb = &HS[(t & 1) * (8 * HROW) + (l16 & 7) * HROW];
        #pragma unroll
        for (int ht = 0; ht < HT; ht++) {
            const half8 ha = *(const half8*)(hb + ht * 32 + quad * 8);
            #pragma unroll
            for (int g = 0; g < 4; g++)
                acc[g] = __builtin_amdgcn_mfma_f32_16x16x32_f16(ha, bf[g][ht], acc[g], 0, 0, 0);
        }
        float hq[2];
        #pragma unroll
        for (int s = 0; s < 2; s++) {
            const int r = hi_rows ? (2 + s) : s;
            const float ig = fast_sigmoid(acc[0][r]);
            const float fg = fast_sigmoid(acc[1][r]);
            const float gg = fast_tanh(acc[2][r]);
            const float og = fast_sigmoid(acc[3][r]);
            const float c  = fg * c_reg[s] + ig * gg;
            c_reg[s] = c;
            hq[s] = og * fast_tanh(c);
        }
        #pragma unroll
        for (int s = 0; s < 2; s++)
            HS[((t + 1) & 1) * (8 * HROW) + (rowbase + s) * HROW + ucol] = (_Float16)hq[s];
        if constexpr (SEQ_OUT) {
            #pragma unroll
            for (int s = 0; s < 2; s++)
                hs_ptr[s * hs_stride] = (_Float16)hq[s];
            hs_ptr += hs_delta;
        } else {
            if (t == T - 1) {
                #pragma unroll
                for (int s = 0; s < 2; s++)
                    hlast[(bbase + rowbase + s) * (2 * U) + dir * U + ucol] = hq[s];
            }
        }
    };

    wait_flag_blk(&lflags[db * 8 + 0], tid);
    half8 za[2], zb[2];
    load_xz(0, za);
    load_xz(1, zb);
    __syncthreads();

    for (int tt = 0; tt < T; tt += 2) {
        if ((tt & 15) == 14 && tt < 126)
            wait_flag_blk(&lflags[db * 8 + ((tt + 2) >> 4)], tid);
        step(tt,     za);
        step(tt + 1, zb);
    }
    __syncthreads();
    if (tid == 0) {
        __threadfence();
        __hip_atomic_fetch_add(done_ctr, 1u, __ATOMIC_RELEASE, SCOPE_AGENT);
    }
}

// ---------------- fused per-layer kernel: 256 rec blocks + 1792 gemm blocks ---
// Gemm tasks (db,tc) in tc-major order (slot = tc*256+db) so every db's chunk-0
// completes in the first task wave; gemm runs ~7 blocks/CU (r8 throughput)
// concurrently with rec consumers. Deadlock-free for any dispatch order.
template<int F_REAL, int FP, int XT, int U, int HT, bool IN_F32, bool STAGE,
         bool SEQ_OUT, bool DENSE>
__global__ __launch_bounds__(256)
void layer_fused(const void* __restrict__ in_,
                 const half8* __restrict__ wfseg, const float4* __restrict__ bfseg,
                 const half8* __restrict__ wrseg,
                 _Float16* __restrict__ xz,
                 _Float16* __restrict__ hseq, float* __restrict__ hlast,
                 unsigned int* __restrict__ lflags, unsigned int* __restrict__ done_ctr,
                 const float* __restrict__ d3_w, const float* __restrict__ d3_b,
                 const float* __restrict__ cls_w, const float* __restrict__ cls_b,
                 float* __restrict__ out)
{
    constexpr int NW = U / 16;
    constexpr int GROUPS = 4 / NW;
    constexpr int TG = NW * 64;
    constexpr int ROWP = FP + 8;
    constexpr int XS_EL = STAGE ? (GROUPS * 2 * 16 * ROWP) : 16;
    constexpr int NGEMM = 1792;

    __shared__ __align__(16) _Float16 XS[XS_EL];
    __shared__ __align__(16) _Float16 HS[2 * 8 * 72];

    const int tid = threadIdx.x;

    if (blockIdx.x < 256) {
        // ---- REC role: latency-critical, boost issue priority ----
        asm volatile("s_setprio 3");
        rec_phase<U, HT, SEQ_OUT>(blockIdx.x, xz, wrseg, hseq, hlast,
                                  lflags, done_ctr, HS, tid);
        asm volatile("s_setprio 0");
        if constexpr (DENSE) {
            wait_count_blk(done_ctr, 256u, tid);
            if (tid < 4) {
                const int r = blockIdx.x * 4 + tid;
                float h[32];
                #pragma unroll
                for (int k = 0; k < 32; k++) h[k] = hlast[r * 32 + k];
                float d1[8];
                #pragma unroll
                for (int j = 0; j < 8; j++) {
                    float a = d3_b[j];
                    #pragma unroll
                    for (int k = 0; k < 32; k++) a += h[k] * d3_w[k * 8 + j];
                    d1[j] = fmaxf(a, 0.0f);
                }
                #pragma unroll
                for (int c = 0; c < 3; c++) {
                    float s = cls_b[c];
                    #pragma unroll
                    for (int j = 0; j < 8; j++) s += d1[j] * cls_w[j * 3 + c];
                    out[r * 3 + c] = 1.0f / (1.0f + __expf(-s));
                }
            }
        }
    } else {
        // ---- GEMM role ----
        const int gb = blockIdx.x - 256;
        const int wave = tid >> 6, lane = tid & 63;
        const int gq = wave / NW, wg = wave - gq * NW;
        const int tid_g = tid & (TG - 1);
        _Float16* XSg = XS + (STAGE ? gq * (2 * 16 * ROWP) : 0);

        for (int slot = gb * GROUPS + gq; slot < 2048; slot += NGEMM * GROUPS) {
            gemm_chunk<F_REAL, FP, XT, U, IN_F32, STAGE>(
                slot & 255, slot >> 8, in_, wfseg, bfseg, xz, XSg, wg, lane, tid_g);
            // publish: drain stores, push to LLC, set flag
            __syncthreads();
            if (tid == 0) __threadfence();
            __syncthreads();
            if (tid_g == 0)
                __hip_atomic_store(&lflags[(slot & 255) * 8 + (slot >> 8)], 1u,
                                   __ATOMIC_RELEASE, SCOPE_AGENT);
        }
    }
}

extern "C" void kernel_launch(void* const* d_in, const int* in_sizes, int n_in,
                              void* d_out, int out_size, void* d_ws, size_t ws_size,
                              hipStream_t stream) {
    const float* x     = (const float*)d_in[0];
    const float* w1f_k = (const float*)d_in[1];
    const float* w1f_r = (const float*)d_in[2];
    const float* w1f_b = (const float*)d_in[3];
    const float* w1b_k = (const float*)d_in[4];
    const float* w1b_r = (const float*)d_in[5];
    const float* w1b_b = (const float*)d_in[6];
    const float* w2f_k = (const float*)d_in[7];
    const float* w2f_r = (const float*)d_in[8];
    const float* w2f_b = (const float*)d_in[9];
    const float* w2b_k = (const float*)d_in[10];
    const float* w2b_r = (const float*)d_in[11];
    const float* w2b_b = (const float*)d_in[12];
    const float* w3f_k = (const float*)d_in[13];
    const float* w3f_r = (const float*)d_in[14];
    const float* w3f_b = (const float*)d_in[15];
    const float* w3b_k = (const float*)d_in[16];
    const float* w3b_r = (const float*)d_in[17];
    const float* w3b_b = (const float*)d_in[18];
    const float* d3_w  = (const float*)d_in[19];
    const float* d3_b  = (const float*)d_in[20];
    const float* cls_w = (const float*)d_in[21];
    const float* cls_b = (const float*)d_in[22];

    char* ws = (char*)d_ws;
    _Float16* xz = (_Float16*)ws;                                   // 134.2MB
    _Float16* h1 = (_Float16*)(ws + 134217728);                     // 32MB
    _Float16* h2 = (_Float16*)(ws + 167772160);                     // 16.8MB
    float*    h3 = (float*)   (ws + 184549376);                     // 128KB
    const size_t B0 = 184680448;
    half8*       wf    = (half8*)      (ws + B0);                   // 176KB
    float4*      bf4   = (float4*)     (ws + B0 + 180224);          // 14KB
    half8*       wrf   = (half8*)      (ws + B0 + 196608);          // 88KB
    unsigned int* flags = (unsigned int*)(ws + B0 + 294912);        // 24KB + ctrs
    unsigned int* done  = flags + 3 * 2048;

    pack_all<<<dim3(8), dim3(256), 0, stream>>>(
        w1f_k, w1f_b, w1b_k, w1b_b, w2f_k, w2f_b, w2b_k, w2b_b,
        w3f_k, w3f_b, w3b_k, w3b_b,
        w1f_r, w1b_r, w2f_r, w2b_r, w3f_r, w3b_r,
        wf, bf4, wrf, flags);

    // L1: F=78 (FP=96, 3 k-tiles), U=64, fp32 in, staged
    layer_fused<78, 96, 3, 64, 2, true, true, true, false>
        <<<dim3(2048), dim3(256), 0, stream>>>(
        x, wf, bf4, wrf, xz, h1, nullptr, flags, done + 0,
        nullptr, nullptr, nullptr, nullptr, nullptr);

    // L2: F=128, U=32, f16 in, staged
    layer_fused<128, 128, 4, 32, 1, false, true, true, false>
        <<<dim3(2048), dim3(256), 0, stream>>>(
        h1, wf + 6144, bf4 + 512, wrf + 4096, xz, h2, nullptr, flags + 2048, done + 1,
        nullptr, nullptr, nullptr, nullptr, nullptr);

    // L3: F=64, U=16, f16 in, direct loads; dense head fused
    layer_fused<64, 64, 2, 16, 1, false, false, false, true>
        <<<dim3(2048), dim3(256), 0, stream>>>(
        h2, wf + 10240, bf4 + 768, wrf + 5120, xz, nullptr, h3, flags + 4096, done + 2,
        d3_w, d3_b, cls_w, cls_b, (float*)d_out);
}